// Round 13
// baseline (85.494 us; speedup 1.0000x reference)
//
#include <hip/hip_runtime.h>
#include <cstdint>
#include <cstddef>

// x[64][1024][32] f32, W[1024][32] f32, b[1024] f32 -> out[64][1024][1024] f32
#define BATCH   64
#define SEQLEN  1024
#define KDIM    32
#define ODIM    1024
#define NTOK    (BATCH * SEQLEN)

typedef __attribute__((ext_vector_type(8))) short bf16x8;   // 8 bf16 = 4 VGPRs
typedef __attribute__((ext_vector_type(4))) float f32x4;

// exact f32 -> bf16 truncation; exact for integer-valued f32 |v| <= 255 and {-1,0,1}
__device__ __forceinline__ unsigned short f32_to_bf16_exact(float f) {
    union { float f; unsigned int u; } cv; cv.f = f;
    return (unsigned short)(cv.u >> 16);
}

// ---------------------------------------------------------------------------
// Monolithic BitLinear kernel: per-block W-scale reduce + inline W ternary
// quant + inline per-token activation quant + MFMA GEMM + bias + in-register
// f32 positional encoding. Single launch — no prep kernel, no xq round-trip,
// no inter-kernel gap.
//
// Tile: 16 s x 256 o x 32 b per block; 512 threads / 8 waves; wave wid ->
// o-quarter (wid&3)*64, b-octet (wid>>2). Grid 512 = 8 XCD x 64; swizzle
// lb=(phys&7)*64+(phys>>3): XCD k owns s-chunks [8k,8k+8) -> its raw-x slice
// is read once from HBM, re-reads L2-hot (the 4 o-blocks sharing a token
// live on the same XCD). Row-assembly: 1 KB/row per block, 4 blocks/row,
// same-XCD L2 (round 11/12-verified optimum for this store family).
// Occupancy: __launch_bounds__(512,4) pins <=128 VGPR -> 2 blocks/CU,
// 16 waves/CU (same as rounds 11/12).
//
// W-scale: every block reduces mean|W| over all 32768 elems in an identical
// deterministic order (thread t owns 64 consecutive elems, 512-entry LDS
// tree) -> same value in every block, no cross-block dependency.
// ---------------------------------------------------------------------------
__global__ __launch_bounds__(512, 4) void bitgemm_mono(
    const float* __restrict__ x,        // [65536][32]
    const float* __restrict__ W,        // [1024][32]
    const float* __restrict__ bias,     // [1024]
    float* __restrict__ out)            // [65536][1024]
{
    __shared__ float red[512];

    const int t    = threadIdx.x;
    const int lane = t & 63;
    const int wid  = t >> 6;              // 0..7
    const int l15  = lane & 15;
    const int hi   = lane >> 4;           // 0..3

    // XCD-aware swizzle (bijective: 512 = 8 XCDs x 64)
    const int lb    = (blockIdx.x & 7) * 64 + (blockIdx.x >> 3);
    const int sblk  = lb >> 3;            // 64 s-chunks (8 per XCD)
    const int oblk  = lb & 3;             // 4 o-blocks of 256
    const int bhalf = (lb >> 2) & 1;      // 2 b-halves of 32
    const int o0    = oblk * 256 + (wid & 3) * 64;   // wave's o-base
    const int s0    = sblk * 16;
    const int bq    = bhalf * 2 + (wid >> 2);        // wave's b-octet 0..3

    // ---- W mean|.| : block-local deterministic reduce (identical all blocks) ----
    {
        const float4* W4 = reinterpret_cast<const float4*>(W) + (size_t)t * 16;
        float acc = 0.f;
        #pragma unroll
        for (int j = 0; j < 16; ++j) {
            float4 v = W4[j];
            acc += fabsf(v.x) + fabsf(v.y) + fabsf(v.z) + fabsf(v.w);
        }
        red[t] = acc;
        __syncthreads();
        for (int step = 256; step > 0; step >>= 1) {
            if (t < step) red[t] += red[t + step];
            __syncthreads();
        }
    }
    const float rw = fmaxf(red[0] * (1.0f / 32768.0f), 1e-5f);  // 1/scale_w
    const float sc = 1.0f / rw;                                 // scale_w

    // ---- A fragments: inline ternary quant of W (once per wave) ----
    bf16x8 afrag[4];
    #pragma unroll
    for (int f = 0; f < 4; ++f) {
        const float* wr = W + (size_t)(o0 + f * 16 + l15) * KDIM + hi * 8;
        float4 wa = *reinterpret_cast<const float4*>(wr);
        float4 wb = *reinterpret_cast<const float4*>(wr + 4);
        float e[8] = {wa.x, wa.y, wa.z, wa.w, wb.x, wb.y, wb.z, wb.w};
        union { bf16x8 v; unsigned short s[8]; } u;
        #pragma unroll
        for (int j = 0; j < 8; ++j)
            u.s[j] = f32_to_bf16_exact(fminf(fmaxf(rintf(e[j] * sc), -1.0f), 1.0f));
        afrag[f] = u.v;
    }

    // ---- bias + positional encoding in-register (once per block) ----
    const float C  = -0.012976281620653759f;  // -log2(10000)/1024
    const float sf = (float)(s0 + l15);
    f32x4 addf[4];
    #pragma unroll
    for (int f = 0; f < 4; ++f) {
        const int oe = o0 + f * 16 + hi * 4;              // multiple of 4
        f32x4 bv = *reinterpret_cast<const f32x4*>(bias + oe);
        float a0 = sf * exp2f(C * (float)oe);
        float a1 = sf * exp2f(C * (float)(oe + 2));
        addf[f][0] = bv[0] + sinf(a0);
        addf[f][1] = bv[1] + cosf(a0);
        addf[f][2] = bv[2] + sinf(a1);
        addf[f][3] = bv[3] + cosf(a1);
    }

    // ---- b-loop: inline activation quant + MFMA + epilogue; 2x unrolled ----
    #pragma unroll 2
    for (int i = 0; i < 16; ++i) {
        const int b   = bq * 16 + i;
        const int tok = (b << 10) + s0 + l15;

        // wave reads 16 token rows x 128 B = 2 KB contiguous raw x
        const float* xr = x + ((size_t)tok << 5) + hi * 8;
        float4 xa = *reinterpret_cast<const float4*>(xr);
        float4 xb = *reinterpret_cast<const float4*>(xr + 4);

        float am = fmaxf(fmaxf(fmaxf(fabsf(xa.x), fabsf(xa.y)),
                               fmaxf(fabsf(xa.z), fabsf(xa.w))),
                         fmaxf(fmaxf(fabsf(xb.x), fabsf(xb.y)),
                               fmaxf(fabsf(xb.z), fabsf(xb.w))));
        // lanes {l15, l15+16, l15+32, l15+48} hold one token's 4 k-slices
        am = fmaxf(am, __shfl_xor(am, 16));
        am = fmaxf(am, __shfl_xor(am, 32));
        am = fmaxf(am, 1e-5f);
        const float xscale = 127.0f / am;     // |v*scale| <= 127: clip can't bind
        union { bf16x8 v; unsigned short s[8]; } bu;
        {
            float e[8] = {xa.x, xa.y, xa.z, xa.w, xb.x, xb.y, xb.z, xb.w};
            #pragma unroll
            for (int j = 0; j < 8; ++j)
                bu.s[j] = f32_to_bf16_exact(rintf(e[j] * xscale)); // int, exact bf16
        }
        const float rxw = am * (1.0f / 127.0f) * rw;  // combined 1/scales

        float* op = out + ((size_t)tok << 10) + o0 + hi * 4;
        #pragma unroll
        for (int f = 0; f < 4; ++f) {
            f32x4 acc = (f32x4){0.f, 0.f, 0.f, 0.f};
            acc = __builtin_amdgcn_mfma_f32_16x16x32_bf16(afrag[f], bu.v, acc, 0, 0, 0);
            f32x4 r;
            #pragma unroll
            for (int j = 0; j < 4; ++j)
                r[j] = fmaf(acc[j], rxw, addf[f][j]);
            *reinterpret_cast<f32x4*>(op + f * 16) = r;
        }
    }
}

// ---------------------------------------------------------------------------
extern "C" void kernel_launch(void* const* d_in, const int* in_sizes, int n_in,
                              void* d_out, int out_size, void* d_ws, size_t ws_size,
                              hipStream_t stream) {
    const float* x = (const float*)d_in[0];   // [64][1024][32]
    const float* W = (const float*)d_in[1];   // [1024][32]
    const float* b = (const float*)d_in[2];   // [1024]
    float* out = (float*)d_out;

    bitgemm_mono<<<512, 512, 0, stream>>>(x, W, b, out);
}